// Round 12
// baseline (379.530 us; speedup 1.0000x reference)
//
#include <hip/hip_runtime.h>
#include <hip/hip_bf16.h>
#include <math.h>

#define NN 100000
#define EE 1600000
#define HD 128
#define GG 128
#define CC 10

#define BKSH 9                    // bucket = dst >> 9 (512 nodes/bucket)
#define NBK  196                  // ceil(100000/512)
#define CH   8192                 // edges per scatter chunk
#define MAXB 12288                // fixed bucket region capacity (mean 8163, +45 sigma)

typedef __attribute__((ext_vector_type(8))) short short8;
typedef __attribute__((ext_vector_type(4))) float f32x4;
typedef __attribute__((ext_vector_type(2))) float f32x2;

// bf16 helpers (RNE)
__device__ __forceinline__ unsigned short f2bf(float f) {
    union { float f; unsigned u; } a; a.f = f;
    unsigned r = a.u + 0x7fff + ((a.u >> 16) & 1);
    return (unsigned short)(r >> 16);
}
__device__ __forceinline__ float bfu(unsigned short u) {
    union { unsigned u; float f; } a; a.u = ((unsigned)u) << 16; return a.f;
}

// fp8 e4m3 pack (HW cvt, 2 values/inst)
__device__ __forceinline__ unsigned pk4fp8(float f0, float f1, float f2, float f3) {
    unsigned u = 0;
    u = __builtin_amdgcn_cvt_pk_fp8_f32(f0, f1, u, false);
    u = __builtin_amdgcn_cvt_pk_fp8_f32(f2, f3, u, true);
    return u;
}

// ---------------- W prep + init (cursor to region bases, pooled/cntg zero) ----------------

__global__ void k_prep_w(const float* __restrict__ w0, const float* __restrict__ w1,
                         const float* __restrict__ w2, unsigned short* __restrict__ Wt,
                         unsigned* __restrict__ cursor, float* __restrict__ pooled,
                         float* __restrict__ cntg) {
    int b = blockIdx.x;
    int t = threadIdx.x;
    if (b == 192) {  // init block
        cursor[t] = (unsigned)(t * MAXB);
        for (int i = t; i < GG * HD; i += 256) pooled[i] = 0.f;
        if (t < GG) cntg[t] = 0.f;
        return;
    }
    int mat = b >> 6;
    int idx = (b & 63) * 256 + t;
    int k = idx >> 7, n = idx & 127;
    const float* Wm = (mat == 0) ? w0 : ((mat == 1) ? w1 : w2);
    Wt[mat * 16384 + n * 128 + k] = f2bf(Wm[k * 128 + n]);
}

// ---------------- scatter packed (src<<9 | dst&511) into FIXED bucket regions ----------------

__global__ __launch_bounds__(512) void k_bscatter(const int* __restrict__ src,
                                                  const int* __restrict__ dst,
                                                  unsigned* __restrict__ cursor,
                                                  unsigned* __restrict__ ebuf) {
    __shared__ unsigned cnt[256], lst[256], gbase[256], ss[256];
    __shared__ unsigned stage[CH];
    __shared__ unsigned char binid[CH];
    int t = threadIdx.x;
    if (t < 256) cnt[t] = 0;
    __syncthreads();
    int base = blockIdx.x * CH;
    int nvalid = EE - base; if (nvalid > CH) nvalid = CH;

    unsigned bk[16], rk[16], pv[16];
#pragma unroll
    for (int k = 0; k < 16; ++k) {
        int e = base + k * 512 + t;
        bk[k] = 0xffffffffu;
        if (e < EE) {
            unsigned d = (unsigned)dst[e];
            unsigned b = d >> BKSH;
            pv[k] = (((unsigned)src[e]) << BKSH) | (d & ((1u << BKSH) - 1));
            bk[k] = b;
            rk[k] = atomicAdd(&cnt[b], 1u);
        }
    }
    __syncthreads();
    unsigned v = 0;
    if (t < 256) { v = cnt[t]; ss[t] = v; }
    __syncthreads();
    for (int off = 1; off < 256; off <<= 1) {
        unsigned a = 0;
        if (t < 256 && t >= off) a = ss[t - off];
        __syncthreads();
        if (t < 256) ss[t] += a;
        __syncthreads();
    }
    if (t < 256) {
        lst[t] = ss[t] - v;
        if (v) gbase[t] = atomicAdd(&cursor[t], v);
    }
    __syncthreads();
#pragma unroll
    for (int k = 0; k < 16; ++k) {
        if (bk[k] != 0xffffffffu) {
            unsigned slot = lst[bk[k]] + rk[k];
            stage[slot] = pv[k];
            binid[slot] = (unsigned char)bk[k];
        }
    }
    __syncthreads();
    for (int j = t; j < nvalid; j += 512) {
        unsigned b = binid[j];
        ebuf[gbase[b] + (j - lst[b])] = stage[j];
    }
}

// ---------------- per-bucket CSR finalize (inline bucket prefix, reg-cached edges) ----------------

__global__ __launch_bounds__(1024) void k_bucket_csr(const unsigned* __restrict__ ebuf,
                                                     const unsigned* __restrict__ cursor,
                                                     int* __restrict__ row_start,
                                                     float* __restrict__ dinv,
                                                     int* __restrict__ col) {
    __shared__ unsigned degl[512], lst[512], lfill[512], ss[512];
    __shared__ unsigned sscan[256];
    __shared__ int colstage[MAXB];
    int t = threadIdx.x, b = blockIdx.x;

    unsigned szv = 0;
    if (t < 256) {
        szv = (t < NBK) ? (cursor[t] - (unsigned)(t * MAXB)) : 0u;
        sscan[t] = szv;
    }
    if (t < 512) { degl[t] = 0; lfill[t] = 0; }
    __syncthreads();
    for (int off = 1; off < 256; off <<= 1) {
        unsigned a = 0;
        if (t < 256 && t >= off) a = sscan[t - off];
        __syncthreads();
        if (t < 256) sscan[t] += a;
        __syncthreads();
    }
    unsigned obase = (b > 0) ? sscan[b - 1] : 0u;
    int size = (int)(sscan[b] - obase);
    unsigned rbase = (unsigned)(b * MAXB);
    int nbase = b << BKSH;
    if (b == 0 && t == 0) row_start[NN] = EE;

    unsigned uv[12];
    int nmine = 0;
    if (size <= MAXB) {
        for (int j = t; j < size; j += 1024) uv[nmine++] = ebuf[rbase + j];
        for (int k = 0; k < nmine; ++k) atomicAdd(&degl[uv[k] & 511u], 1u);
    } else {
        for (int j = t; j < size; j += 1024) atomicAdd(&degl[ebuf[rbase + j] & 511u], 1u);
    }
    __syncthreads();
    unsigned v = 0;
    if (t < 512) { v = degl[t]; ss[t] = v; }
    __syncthreads();
    for (int off = 1; off < 512; off <<= 1) {
        unsigned a = 0;
        if (t < 512 && t >= off) a = ss[t - off];
        __syncthreads();
        if (t < 512) ss[t] += a;
        __syncthreads();
    }
    if (t < 512) {
        lst[t] = ss[t] - v;
        int node = nbase + t;
        if (node < NN) {
            row_start[node] = (int)(obase + lst[t]);
            dinv[node] = rsqrtf((float)(v + 1));
        }
    }
    __syncthreads();
    if (size <= MAXB) {
        for (int k = 0; k < nmine; ++k) {
            unsigned u = uv[k];
            unsigned l = u & 511u;
            unsigned pos = lst[l] + atomicAdd(&lfill[l], 1u);
            colstage[pos] = (int)(u >> BKSH);
        }
        __syncthreads();
        for (int j = t; j < size; j += 1024) col[obase + j] = colstage[j];
    } else {
        for (int j = t; j < size; j += 1024) {
            unsigned u = ebuf[rbase + j];
            unsigned l = u & 511u;
            unsigned pos = lst[l] + atomicAdd(&lfill[l], 1u);
            col[obase + pos] = (int)(u >> BKSH);
        }
    }
}

// ---------------- GEMM (MFMA bf16): g8 = fp8(dinv ⊙ (A @ W)) ----------------
// No Ws LDS staging: W fragments come straight from global (L2-resident, 32KB).
// LDS 69.6 -> 34.8 KB: 4 blocks/CU instead of 2.

#define LDK 136  // ushort stride

template <bool F32IN>
__global__ __launch_bounds__(256) void k_gemm_mfma(
    const void* __restrict__ Ap, const unsigned short* __restrict__ Wt,
    const float* __restrict__ dinv, unsigned* __restrict__ g8) {
    __shared__ unsigned short As[128 * LDK];  // A tile [row][k]; reused as C tile
    __shared__ float dv[128];
    int t = threadIdx.x;
    int r0 = blockIdx.x * 128;

#pragma unroll
    for (int p = 0; p < 8; ++p) {
        int chunk = p * 256 + t;
        int row = chunk >> 4, kc = chunk & 15;
        uint4 sv = make_uint4(0u, 0u, 0u, 0u);
        if (F32IN) {
            const float* A = (const float*)Ap;
            if (r0 + row < NN) {
                const float* ap = A + (size_t)(r0 + row) * HD + kc * 8;
                float4 va = *(const float4*)ap;
                float4 vb = *(const float4*)(ap + 4);
                sv.x = (unsigned)f2bf(va.x) | ((unsigned)f2bf(va.y) << 16);
                sv.y = (unsigned)f2bf(va.z) | ((unsigned)f2bf(va.w) << 16);
                sv.z = (unsigned)f2bf(vb.x) | ((unsigned)f2bf(vb.y) << 16);
                sv.w = (unsigned)f2bf(vb.z) | ((unsigned)f2bf(vb.w) << 16);
            }
        } else {
            const unsigned short* A = (const unsigned short*)Ap;
            if (r0 + row < NN) sv = *(const uint4*)(A + (size_t)(r0 + row) * HD + kc * 8);
        }
        *(uint4*)(As + row * LDK + kc * 8) = sv;
    }
    if (t < 128) dv[t] = (r0 + t < NN) ? dinv[r0 + t] : 0.f;
    __syncthreads();

    int wave = t >> 6, lane = t & 63, quad = lane >> 4, l16 = lane & 15;
    int wr = (wave >> 1) * 64, wc = (wave & 1) * 64;

    f32x4 acc[4][4];
#pragma unroll
    for (int i = 0; i < 4; ++i)
#pragma unroll
        for (int j = 0; j < 4; ++j) acc[i][j] = (f32x4){0.f, 0.f, 0.f, 0.f};

#pragma unroll
    for (int kk = 0; kk < 4; ++kk) {
        int k0 = kk * 32 + quad * 8;
        short8 af[4], bfr[4];
#pragma unroll
        for (int i = 0; i < 4; ++i)
            af[i] = *(const short8*)(As + (wr + i * 16 + l16) * LDK + k0);
#pragma unroll
        for (int j = 0; j < 4; ++j)
            bfr[j] = *(const short8*)(Wt + (size_t)(wc + j * 16 + l16) * HD + k0);
#pragma unroll
        for (int i = 0; i < 4; ++i)
#pragma unroll
            for (int j = 0; j < 4; ++j)
                acc[i][j] = __builtin_amdgcn_mfma_f32_16x16x32_bf16(af[i], bfr[j], acc[i][j], 0, 0, 0);
    }
    __syncthreads();

#pragma unroll
    for (int i = 0; i < 4; ++i) {
        int lr = wr + i * 16 + quad * 4;
#pragma unroll
        for (int reg = 0; reg < 4; ++reg) {
            float sc = dv[lr + reg];
#pragma unroll
            for (int j = 0; j < 4; ++j)
                As[(lr + reg) * LDK + wc + j * 16 + l16] = f2bf(acc[i][j][reg] * sc);
        }
    }
    __syncthreads();

    int row = t >> 1, half = t & 1;
    if (r0 + row < NN) {
        const unsigned short* sp = As + row * LDK + half * 64;
        unsigned og[16];
#pragma unroll
        for (int q = 0; q < 16; ++q)
            og[q] = pk4fp8(bfu(sp[4 * q]), bfu(sp[4 * q + 1]),
                           bfu(sp[4 * q + 2]), bfu(sp[4 * q + 3]));
        uint4* dp = (uint4*)(g8 + (size_t)(r0 + row) * 32 + half * 16);
#pragma unroll
        for (int q = 0; q < 4; ++q)
            dp[q] = make_uint4(og[4 * q], og[4 * q + 1], og[4 * q + 2], og[4 * q + 3]);
    }
}

// ---------------- aggregation: hA = bf16(relu(dinv*(g[d]+sum g[s])+b)) ----------------
// Half-wave per node + col software-prefetch. `nbase` lets the launch split the
// node range into two dispatches (diagnostic: surfaces sub-46us kernels in top-5).

__global__ __launch_bounds__(256) void k_aggregate(
    const unsigned* __restrict__ g8, const int* __restrict__ row_start,
    const int* __restrict__ col, const float* __restrict__ dinv,
    const float* __restrict__ bias, uint2* __restrict__ out, int nbase) {
    int node = nbase + blockIdx.x * 8 + (threadIdx.x >> 5);
    int l = threadIdx.x & 31;
    unsigned su = g8[node * 32 + l];  // self loop
    f32x2 a01 = __builtin_amdgcn_cvt_pk_f32_fp8(su, false);
    f32x2 a23 = __builtin_amdgcn_cvt_pk_f32_fp8(su, true);
    int e = row_start[node], end = row_start[node + 1];

    int c0 = 0, c1 = 0, c2 = 0, c3 = 0, c4 = 0, c5 = 0, c6 = 0, c7 = 0;
    bool have = (e + 8 <= end);
    if (have) {
        c0 = col[e];     c1 = col[e + 1]; c2 = col[e + 2]; c3 = col[e + 3];
        c4 = col[e + 4]; c5 = col[e + 5]; c6 = col[e + 6]; c7 = col[e + 7];
    }
    while (have) {
        unsigned u0 = g8[c0 * 32 + l];
        unsigned u1 = g8[c1 * 32 + l];
        unsigned u2 = g8[c2 * 32 + l];
        unsigned u3 = g8[c3 * 32 + l];
        unsigned u4 = g8[c4 * 32 + l];
        unsigned u5 = g8[c5 * 32 + l];
        unsigned u6 = g8[c6 * 32 + l];
        unsigned u7 = g8[c7 * 32 + l];
        int ne = e + 8;
        bool nhave = (ne + 8 <= end);
        int n0 = c0, n1 = c1, n2 = c2, n3 = c3, n4 = c4, n5 = c5, n6 = c6, n7 = c7;
        if (nhave) {
            n0 = col[ne];     n1 = col[ne + 1]; n2 = col[ne + 2]; n3 = col[ne + 3];
            n4 = col[ne + 4]; n5 = col[ne + 5]; n6 = col[ne + 6]; n7 = col[ne + 7];
        }
#pragma unroll
        for (int q = 0; q < 8; ++q) {
            unsigned u = (q == 0) ? u0 : (q == 1) ? u1 : (q == 2) ? u2 : (q == 3) ? u3
                       : (q == 4) ? u4 : (q == 5) ? u5 : (q == 6) ? u6 : u7;
            a01 += __builtin_amdgcn_cvt_pk_f32_fp8(u, false);
            a23 += __builtin_amdgcn_cvt_pk_f32_fp8(u, true);
        }
        e = ne; have = nhave;
        c0 = n0; c1 = n1; c2 = n2; c3 = n3; c4 = n4; c5 = n5; c6 = n6; c7 = n7;
    }
    for (; e < end; ++e) {
        unsigned u = g8[col[e] * 32 + l];
        a01 += __builtin_amdgcn_cvt_pk_f32_fp8(u, false);
        a23 += __builtin_amdgcn_cvt_pk_f32_fp8(u, true);
    }
    float sc = dinv[node];
    float4 bb = ((const float4*)bias)[l];
    float r0 = fmaxf(fmaf(a01.x, sc, bb.x), 0.f);
    float r1 = fmaxf(fmaf(a01.y, sc, bb.y), 0.f);
    float r2 = fmaxf(fmaf(a23.x, sc, bb.z), 0.f);
    float r3 = fmaxf(fmaf(a23.y, sc, bb.w), 0.f);
    uint2 o;
    o.x = (unsigned)f2bf(r0) | ((unsigned)f2bf(r1) << 16);
    o.y = (unsigned)f2bf(r2) | ((unsigned)f2bf(r3) << 16);
    out[node * 32 + l] = o;
}

// ---------------- parallel mean-pool: partial sums via f32 atomics ----------------

__global__ __launch_bounds__(256) void k_pool_partial(
    const unsigned short* __restrict__ h, const int* __restrict__ batch,
    float* __restrict__ pooled, float* __restrict__ cntg) {
    int t = threadIdx.x;
    int slot = t >> 7, feat = t & 127;
    int base = blockIdx.x * 128;
    int endr = base + 128; if (endr > NN) endr = NN;
    float acc = 0.f;
    int cur = -1, run = 0;
    for (int r = base + slot; r < endr; r += 2) {
        int g = batch[r];
        float v = bfu(h[(size_t)r * HD + feat]);
        if (g != cur) {
            if (cur >= 0) {
                atomicAdd(&pooled[cur * HD + feat], acc);
                if (feat == 0) atomicAdd(&cntg[cur], (float)run);
            }
            cur = g; acc = 0.f; run = 0;
        }
        acc += v; ++run;
    }
    if (cur >= 0) {
        atomicAdd(&pooled[cur * HD + feat], acc);
        if (feat == 0) atomicAdd(&cntg[cur], (float)run);
    }
}

// ---------------- head: mean -> relu(W1) -> W2 -> log_softmax ----------------

__global__ __launch_bounds__(128) void k_head(const float* __restrict__ pooled,
                                              const float* __restrict__ cntg,
                                              const float* __restrict__ w1,
                                              const float* __restrict__ b1,
                                              const float* __restrict__ w2,
                                              const float* __restrict__ b2,
                                              float* __restrict__ out) {
    __shared__ float row[HD], hrow[HD], logits[CC];
    int g = blockIdx.x, t = threadIdx.x;
    row[t] = pooled[g * HD + t] / fmaxf(cntg[g], 1.f);
    __syncthreads();
    float acc = b1[t];
    for (int k = 0; k < HD; ++k) acc = fmaf(row[k], w1[k * HD + t], acc);
    hrow[t] = fmaxf(acc, 0.f);
    __syncthreads();
    if (t < CC) {
        float a = b2[t];
        for (int k = 0; k < HD; ++k) a = fmaf(hrow[k], w2[k * CC + t], a);
        logits[t] = a;
    }
    __syncthreads();
    if (t < CC) {
        float m = logits[0];
        for (int i = 1; i < CC; ++i) m = fmaxf(m, logits[i]);
        float s = 0.f;
        for (int i = 0; i < CC; ++i) s += expf(logits[i] - m);
        out[g * CC + t] = logits[t] - m - logf(s);
    }
}

// ---------------- launch ----------------

extern "C" void kernel_launch(void* const* d_in, const int* in_sizes, int n_in,
                              void* d_out, int out_size, void* d_ws, size_t ws_size,
                              hipStream_t stream) {
    const float* x      = (const float*)d_in[0];
    const int*   ei     = (const int*)d_in[1];   // [2,E]: row0=src, row1=dst
    const int*   batch  = (const int*)d_in[2];
    const float* w_init = (const float*)d_in[3];
    const float* b_init = (const float*)d_in[4];
    const float* w_conv = (const float*)d_in[5];  // [2,128,128]
    const float* b_conv = (const float*)d_in[6];  // [2,128]
    const float* w_h1   = (const float*)d_in[7];
    const float* b_h1   = (const float*)d_in[8];
    const float* w_h2   = (const float*)d_in[9];
    const float* b_h2   = (const float*)d_in[10];
    float* out = (float*)d_out;
    (void)n_in; (void)in_sizes; (void)out_size; (void)ws_size;

    char* ws = (char*)d_ws;
    size_t off = 0;
    auto alloc = [&](size_t bytes) -> void* {
        void* p = ws + off;
        off += (bytes + 255) & ~(size_t)255;
        return p;
    };
    unsigned short* hAbf         = (unsigned short*)alloc((size_t)NN * HD * 2);  // bf16 node state
    unsigned*       g8           = (unsigned*)alloc((size_t)NN * 32 * 4);        // fp8 messages 12.8MB
    unsigned short* Wt           = (unsigned short*)alloc(3 * 16384 * 2);
    float*          dinv         = (float*)alloc((size_t)NN * 4);
    int*            row_start    = (int*)alloc((size_t)(NN + 1) * 4);
    int*            col          = (int*)alloc((size_t)EE * 4);
    unsigned*       ebuf         = (unsigned*)alloc((size_t)NBK * MAXB * 4);     // fixed regions 9.6MB
    unsigned*       cursor       = (unsigned*)alloc(256 * 4);
    float*          pooled       = (float*)alloc((size_t)GG * HD * 4);
    float*          cntg         = (float*)alloc((size_t)GG * 4);

    const int* srcp = ei;
    const int* dstp = ei + EE;

    k_prep_w<<<193, 256, 0, stream>>>(w_init, w_conv, w_conv + HD * HD, Wt,
                                      cursor, pooled, cntg);

    int nchunks = (EE + CH - 1) / CH;  // 196
    k_bscatter<<<nchunks, 512, 0, stream>>>(srcp, dstp, cursor, ebuf);
    k_bucket_csr<<<NBK, 1024, 0, stream>>>(ebuf, cursor, row_start, dinv, col);

    int gemm_grid = (NN + 127) / 128;  // 782
    int agg_half = NN / 16;            // 6250 blocks per half-dispatch

    // layer 1 (f32 input)
    k_gemm_mfma<true><<<gemm_grid, 256, 0, stream>>>(x, Wt, dinv, g8);
    k_aggregate<<<agg_half, 256, 0, stream>>>(g8, row_start, col, dinv, b_init, (uint2*)hAbf, 0);
    k_aggregate<<<agg_half, 256, 0, stream>>>(g8, row_start, col, dinv, b_init, (uint2*)hAbf, NN / 2);
    // layer 2
    k_gemm_mfma<false><<<gemm_grid, 256, 0, stream>>>(hAbf, Wt + 16384, dinv, g8);
    k_aggregate<<<agg_half, 256, 0, stream>>>(g8, row_start, col, dinv, b_conv, (uint2*)hAbf, 0);
    k_aggregate<<<agg_half, 256, 0, stream>>>(g8, row_start, col, dinv, b_conv, (uint2*)hAbf, NN / 2);
    // layer 3
    k_gemm_mfma<false><<<gemm_grid, 256, 0, stream>>>(hAbf, Wt + 2 * 16384, dinv, g8);
    k_aggregate<<<agg_half, 256, 0, stream>>>(g8, row_start, col, dinv, b_conv + HD, (uint2*)hAbf, 0);
    k_aggregate<<<agg_half, 256, 0, stream>>>(g8, row_start, col, dinv, b_conv + HD, (uint2*)hAbf, NN / 2);

    k_pool_partial<<<(NN + 127) / 128, 256, 0, stream>>>(hAbf, batch, pooled, cntg);
    k_head<<<GG, 128, 0, stream>>>(pooled, cntg, w_h1, b_h1, w_h2, b_h2, out);
}

// Round 13
// 351.647 us; speedup vs baseline: 1.0793x; 1.0793x over previous
//
#include <hip/hip_runtime.h>
#include <hip/hip_bf16.h>
#include <math.h>

#define NN 100000
#define EE 1600000
#define HD 128
#define GG 128
#define CC 10

#define BKSH 9                    // bucket = dst >> 9 (512 nodes/bucket)
#define NBK  196                  // ceil(100000/512)
#define CH   8192                 // edges per scatter chunk
#define MAXB 12288                // fixed bucket region capacity (mean 8163, +45 sigma)

typedef __attribute__((ext_vector_type(8))) short short8;
typedef __attribute__((ext_vector_type(4))) float f32x4;
typedef __attribute__((ext_vector_type(2))) float f32x2;

// bf16 helpers (RNE)
__device__ __forceinline__ unsigned short f2bf(float f) {
    union { float f; unsigned u; } a; a.f = f;
    unsigned r = a.u + 0x7fff + ((a.u >> 16) & 1);
    return (unsigned short)(r >> 16);
}
__device__ __forceinline__ float bfu(unsigned short u) {
    union { unsigned u; float f; } a; a.u = ((unsigned)u) << 16; return a.f;
}

// fp8 e4m3 pack (HW cvt, 2 values/inst)
__device__ __forceinline__ unsigned pk4fp8(float f0, float f1, float f2, float f3) {
    unsigned u = 0;
    u = __builtin_amdgcn_cvt_pk_fp8_f32(f0, f1, u, false);
    u = __builtin_amdgcn_cvt_pk_fp8_f32(f2, f3, u, true);
    return u;
}

// ---------------- W prep + init (cursor to region bases, pooled/cntg zero) ----------------

__global__ void k_prep_w(const float* __restrict__ w0, const float* __restrict__ w1,
                         const float* __restrict__ w2, unsigned short* __restrict__ Wt,
                         unsigned* __restrict__ cursor, float* __restrict__ pooled,
                         float* __restrict__ cntg) {
    int b = blockIdx.x;
    int t = threadIdx.x;
    if (b == 192) {  // init block
        cursor[t] = (unsigned)(t * MAXB);
        for (int i = t; i < GG * HD; i += 256) pooled[i] = 0.f;
        if (t < GG) cntg[t] = 0.f;
        return;
    }
    int mat = b >> 6;
    int idx = (b & 63) * 256 + t;
    int k = idx >> 7, n = idx & 127;
    const float* Wm = (mat == 0) ? w0 : ((mat == 1) ? w1 : w2);
    Wt[mat * 16384 + n * 128 + k] = f2bf(Wm[k * 128 + n]);
}

// ---------------- scatter packed (src<<9 | dst&511) into FIXED bucket regions ----------------

__global__ __launch_bounds__(512) void k_bscatter(const int* __restrict__ src,
                                                  const int* __restrict__ dst,
                                                  unsigned* __restrict__ cursor,
                                                  unsigned* __restrict__ ebuf) {
    __shared__ unsigned cnt[256], lst[256], gbase[256], ss[256];
    __shared__ unsigned stage[CH];
    __shared__ unsigned char binid[CH];
    int t = threadIdx.x;
    if (t < 256) cnt[t] = 0;
    __syncthreads();
    int base = blockIdx.x * CH;
    int nvalid = EE - base; if (nvalid > CH) nvalid = CH;

    unsigned bk[16], rk[16], pv[16];
#pragma unroll
    for (int k = 0; k < 16; ++k) {
        int e = base + k * 512 + t;
        bk[k] = 0xffffffffu;
        if (e < EE) {
            unsigned d = (unsigned)dst[e];
            unsigned b = d >> BKSH;
            pv[k] = (((unsigned)src[e]) << BKSH) | (d & ((1u << BKSH) - 1));
            bk[k] = b;
            rk[k] = atomicAdd(&cnt[b], 1u);
        }
    }
    __syncthreads();
    unsigned v = 0;
    if (t < 256) { v = cnt[t]; ss[t] = v; }
    __syncthreads();
    for (int off = 1; off < 256; off <<= 1) {
        unsigned a = 0;
        if (t < 256 && t >= off) a = ss[t - off];
        __syncthreads();
        if (t < 256) ss[t] += a;
        __syncthreads();
    }
    if (t < 256) {
        lst[t] = ss[t] - v;
        if (v) gbase[t] = atomicAdd(&cursor[t], v);
    }
    __syncthreads();
#pragma unroll
    for (int k = 0; k < 16; ++k) {
        if (bk[k] != 0xffffffffu) {
            unsigned slot = lst[bk[k]] + rk[k];
            stage[slot] = pv[k];
            binid[slot] = (unsigned char)bk[k];
        }
    }
    __syncthreads();
    for (int j = t; j < nvalid; j += 512) {
        unsigned b = binid[j];
        ebuf[gbase[b] + (j - lst[b])] = stage[j];
    }
}

// ---------------- per-bucket CSR finalize (inline bucket prefix, reg-cached edges) ----------------

__global__ __launch_bounds__(1024) void k_bucket_csr(const unsigned* __restrict__ ebuf,
                                                     const unsigned* __restrict__ cursor,
                                                     int* __restrict__ row_start,
                                                     float* __restrict__ dinv,
                                                     int* __restrict__ col) {
    __shared__ unsigned degl[512], lst[512], lfill[512], ss[512];
    __shared__ unsigned sscan[256];
    __shared__ int colstage[MAXB];
    int t = threadIdx.x, b = blockIdx.x;

    unsigned szv = 0;
    if (t < 256) {
        szv = (t < NBK) ? (cursor[t] - (unsigned)(t * MAXB)) : 0u;
        sscan[t] = szv;
    }
    if (t < 512) { degl[t] = 0; lfill[t] = 0; }
    __syncthreads();
    for (int off = 1; off < 256; off <<= 1) {
        unsigned a = 0;
        if (t < 256 && t >= off) a = sscan[t - off];
        __syncthreads();
        if (t < 256) sscan[t] += a;
        __syncthreads();
    }
    unsigned obase = (b > 0) ? sscan[b - 1] : 0u;
    int size = (int)(sscan[b] - obase);
    unsigned rbase = (unsigned)(b * MAXB);
    int nbase = b << BKSH;
    if (b == 0 && t == 0) row_start[NN] = EE;

    unsigned uv[12];
    int nmine = 0;
    if (size <= MAXB) {
        for (int j = t; j < size; j += 1024) uv[nmine++] = ebuf[rbase + j];
        for (int k = 0; k < nmine; ++k) atomicAdd(&degl[uv[k] & 511u], 1u);
    } else {
        for (int j = t; j < size; j += 1024) atomicAdd(&degl[ebuf[rbase + j] & 511u], 1u);
    }
    __syncthreads();
    unsigned v = 0;
    if (t < 512) { v = degl[t]; ss[t] = v; }
    __syncthreads();
    for (int off = 1; off < 512; off <<= 1) {
        unsigned a = 0;
        if (t < 512 && t >= off) a = ss[t - off];
        __syncthreads();
        if (t < 512) ss[t] += a;
        __syncthreads();
    }
    if (t < 512) {
        lst[t] = ss[t] - v;
        int node = nbase + t;
        if (node < NN) {
            row_start[node] = (int)(obase + lst[t]);
            dinv[node] = rsqrtf((float)(v + 1));
        }
    }
    __syncthreads();
    if (size <= MAXB) {
        for (int k = 0; k < nmine; ++k) {
            unsigned u = uv[k];
            unsigned l = u & 511u;
            unsigned pos = lst[l] + atomicAdd(&lfill[l], 1u);
            colstage[pos] = (int)(u >> BKSH);
        }
        __syncthreads();
        for (int j = t; j < size; j += 1024) col[obase + j] = colstage[j];
    } else {
        for (int j = t; j < size; j += 1024) {
            unsigned u = ebuf[rbase + j];
            unsigned l = u & 511u;
            unsigned pos = lst[l] + atomicAdd(&lfill[l], 1u);
            col[obase + pos] = (int)(u >> BKSH);
        }
    }
}

// ---------------- GEMM (MFMA bf16): g8 = fp8(dinv ⊙ (A @ W)) ----------------
// Ws staged in LDS (r12 showed global-W costs ~+6us/GEMM: L2 latency on the
// MFMA critical path beats the occupancy gain).

#define LDK 136  // ushort stride

template <bool F32IN>
__global__ __launch_bounds__(256) void k_gemm_mfma(
    const void* __restrict__ Ap, const unsigned short* __restrict__ Wt,
    const float* __restrict__ dinv, unsigned* __restrict__ g8) {
    __shared__ unsigned short As[128 * LDK];  // A tile [row][k]; reused as C tile
    __shared__ unsigned short Ws[128 * LDK];  // Wt tile [n][k]
    __shared__ float dv[128];
    int t = threadIdx.x;
    int r0 = blockIdx.x * 128;

#pragma unroll
    for (int p = 0; p < 8; ++p) {
        int chunk = p * 256 + t;
        int row = chunk >> 4, kc = chunk & 15;
        uint4 sv = make_uint4(0u, 0u, 0u, 0u);
        if (F32IN) {
            const float* A = (const float*)Ap;
            if (r0 + row < NN) {
                const float* ap = A + (size_t)(r0 + row) * HD + kc * 8;
                float4 va = *(const float4*)ap;
                float4 vb = *(const float4*)(ap + 4);
                sv.x = (unsigned)f2bf(va.x) | ((unsigned)f2bf(va.y) << 16);
                sv.y = (unsigned)f2bf(va.z) | ((unsigned)f2bf(va.w) << 16);
                sv.z = (unsigned)f2bf(vb.x) | ((unsigned)f2bf(vb.y) << 16);
                sv.w = (unsigned)f2bf(vb.z) | ((unsigned)f2bf(vb.w) << 16);
            }
        } else {
            const unsigned short* A = (const unsigned short*)Ap;
            if (r0 + row < NN) sv = *(const uint4*)(A + (size_t)(r0 + row) * HD + kc * 8);
        }
        *(uint4*)(As + row * LDK + kc * 8) = sv;
        uint4 w = *(const uint4*)(Wt + (size_t)row * HD + kc * 8);
        *(uint4*)(Ws + row * LDK + kc * 8) = w;
    }
    if (t < 128) dv[t] = (r0 + t < NN) ? dinv[r0 + t] : 0.f;
    __syncthreads();

    int wave = t >> 6, lane = t & 63, quad = lane >> 4, l16 = lane & 15;
    int wr = (wave >> 1) * 64, wc = (wave & 1) * 64;

    f32x4 acc[4][4];
#pragma unroll
    for (int i = 0; i < 4; ++i)
#pragma unroll
        for (int j = 0; j < 4; ++j) acc[i][j] = (f32x4){0.f, 0.f, 0.f, 0.f};

#pragma unroll
    for (int kk = 0; kk < 4; ++kk) {
        int k0 = kk * 32 + quad * 8;
        short8 af[4], bfr[4];
#pragma unroll
        for (int i = 0; i < 4; ++i)
            af[i] = *(const short8*)(As + (wr + i * 16 + l16) * LDK + k0);
#pragma unroll
        for (int j = 0; j < 4; ++j)
            bfr[j] = *(const short8*)(Ws + (wc + j * 16 + l16) * LDK + k0);
#pragma unroll
        for (int i = 0; i < 4; ++i)
#pragma unroll
            for (int j = 0; j < 4; ++j)
                acc[i][j] = __builtin_amdgcn_mfma_f32_16x16x32_bf16(af[i], bfr[j], acc[i][j], 0, 0, 0);
    }
    __syncthreads();

#pragma unroll
    for (int i = 0; i < 4; ++i) {
        int lr = wr + i * 16 + quad * 4;
#pragma unroll
        for (int reg = 0; reg < 4; ++reg) {
            float sc = dv[lr + reg];
#pragma unroll
            for (int j = 0; j < 4; ++j)
                As[(lr + reg) * LDK + wc + j * 16 + l16] = f2bf(acc[i][j][reg] * sc);
        }
    }
    __syncthreads();

    int row = t >> 1, half = t & 1;
    if (r0 + row < NN) {
        const unsigned short* sp = As + row * LDK + half * 64;
        unsigned og[16];
#pragma unroll
        for (int q = 0; q < 16; ++q)
            og[q] = pk4fp8(bfu(sp[4 * q]), bfu(sp[4 * q + 1]),
                           bfu(sp[4 * q + 2]), bfu(sp[4 * q + 3]));
        uint4* dp = (uint4*)(g8 + (size_t)(r0 + row) * 32 + half * 16);
#pragma unroll
        for (int q = 0; q < 4; ++q)
            dp[q] = make_uint4(og[4 * q], og[4 * q + 1], og[4 * q + 2], og[4 * q + 3]);
    }
}

// ---------------- aggregation: hA = bf16(relu(dinv*(g[d]+sum g[s])+b)) ----------------
// Half-wave per node + col software-prefetch. At the random-128B-line service
// floor (~35 G lines/s, plateau across r7-r11 implementations).

__global__ __launch_bounds__(256) void k_aggregate(
    const unsigned* __restrict__ g8, const int* __restrict__ row_start,
    const int* __restrict__ col, const float* __restrict__ dinv,
    const float* __restrict__ bias, uint2* __restrict__ out) {
    int node = blockIdx.x * 8 + (threadIdx.x >> 5);  // grid*8 == NN exactly
    int l = threadIdx.x & 31;
    unsigned su = g8[node * 32 + l];  // self loop
    f32x2 a01 = __builtin_amdgcn_cvt_pk_f32_fp8(su, false);
    f32x2 a23 = __builtin_amdgcn_cvt_pk_f32_fp8(su, true);
    int e = row_start[node], end = row_start[node + 1];

    int c0 = 0, c1 = 0, c2 = 0, c3 = 0, c4 = 0, c5 = 0, c6 = 0, c7 = 0;
    bool have = (e + 8 <= end);
    if (have) {
        c0 = col[e];     c1 = col[e + 1]; c2 = col[e + 2]; c3 = col[e + 3];
        c4 = col[e + 4]; c5 = col[e + 5]; c6 = col[e + 6]; c7 = col[e + 7];
    }
    while (have) {
        unsigned u0 = g8[c0 * 32 + l];
        unsigned u1 = g8[c1 * 32 + l];
        unsigned u2 = g8[c2 * 32 + l];
        unsigned u3 = g8[c3 * 32 + l];
        unsigned u4 = g8[c4 * 32 + l];
        unsigned u5 = g8[c5 * 32 + l];
        unsigned u6 = g8[c6 * 32 + l];
        unsigned u7 = g8[c7 * 32 + l];
        int ne = e + 8;
        bool nhave = (ne + 8 <= end);
        int n0 = c0, n1 = c1, n2 = c2, n3 = c3, n4 = c4, n5 = c5, n6 = c6, n7 = c7;
        if (nhave) {
            n0 = col[ne];     n1 = col[ne + 1]; n2 = col[ne + 2]; n3 = col[ne + 3];
            n4 = col[ne + 4]; n5 = col[ne + 5]; n6 = col[ne + 6]; n7 = col[ne + 7];
        }
#pragma unroll
        for (int q = 0; q < 8; ++q) {
            unsigned u = (q == 0) ? u0 : (q == 1) ? u1 : (q == 2) ? u2 : (q == 3) ? u3
                       : (q == 4) ? u4 : (q == 5) ? u5 : (q == 6) ? u6 : u7;
            a01 += __builtin_amdgcn_cvt_pk_f32_fp8(u, false);
            a23 += __builtin_amdgcn_cvt_pk_f32_fp8(u, true);
        }
        e = ne; have = nhave;
        c0 = n0; c1 = n1; c2 = n2; c3 = n3; c4 = n4; c5 = n5; c6 = n6; c7 = n7;
    }
    for (; e < end; ++e) {
        unsigned u = g8[col[e] * 32 + l];
        a01 += __builtin_amdgcn_cvt_pk_f32_fp8(u, false);
        a23 += __builtin_amdgcn_cvt_pk_f32_fp8(u, true);
    }
    float sc = dinv[node];
    float4 bb = ((const float4*)bias)[l];
    float r0 = fmaxf(fmaf(a01.x, sc, bb.x), 0.f);
    float r1 = fmaxf(fmaf(a01.y, sc, bb.y), 0.f);
    float r2 = fmaxf(fmaf(a23.x, sc, bb.z), 0.f);
    float r3 = fmaxf(fmaf(a23.y, sc, bb.w), 0.f);
    uint2 o;
    o.x = (unsigned)f2bf(r0) | ((unsigned)f2bf(r1) << 16);
    o.y = (unsigned)f2bf(r2) | ((unsigned)f2bf(r3) << 16);
    out[node * 32 + l] = o;
}

// ---------------- parallel mean-pool: partial sums via f32 atomics ----------------

__global__ __launch_bounds__(256) void k_pool_partial(
    const unsigned short* __restrict__ h, const int* __restrict__ batch,
    float* __restrict__ pooled, float* __restrict__ cntg) {
    int t = threadIdx.x;
    int slot = t >> 7, feat = t & 127;
    int base = blockIdx.x * 128;
    int endr = base + 128; if (endr > NN) endr = NN;
    float acc = 0.f;
    int cur = -1, run = 0;
    for (int r = base + slot; r < endr; r += 2) {
        int g = batch[r];
        float v = bfu(h[(size_t)r * HD + feat]);
        if (g != cur) {
            if (cur >= 0) {
                atomicAdd(&pooled[cur * HD + feat], acc);
                if (feat == 0) atomicAdd(&cntg[cur], (float)run);
            }
            cur = g; acc = 0.f; run = 0;
        }
        acc += v; ++run;
    }
    if (cur >= 0) {
        atomicAdd(&pooled[cur * HD + feat], acc);
        if (feat == 0) atomicAdd(&cntg[cur], (float)run);
    }
}

// ---------------- head: mean -> relu(W1) -> W2 -> log_softmax ----------------

__global__ __launch_bounds__(128) void k_head(const float* __restrict__ pooled,
                                              const float* __restrict__ cntg,
                                              const float* __restrict__ w1,
                                              const float* __restrict__ b1,
                                              const float* __restrict__ w2,
                                              const float* __restrict__ b2,
                                              float* __restrict__ out) {
    __shared__ float row[HD], hrow[HD], logits[CC];
    int g = blockIdx.x, t = threadIdx.x;
    row[t] = pooled[g * HD + t] / fmaxf(cntg[g], 1.f);
    __syncthreads();
    float acc = b1[t];
    for (int k = 0; k < HD; ++k) acc = fmaf(row[k], w1[k * HD + t], acc);
    hrow[t] = fmaxf(acc, 0.f);
    __syncthreads();
    if (t < CC) {
        float a = b2[t];
        for (int k = 0; k < HD; ++k) a = fmaf(hrow[k], w2[k * CC + t], a);
        logits[t] = a;
    }
    __syncthreads();
    if (t < CC) {
        float m = logits[0];
        for (int i = 1; i < CC; ++i) m = fmaxf(m, logits[i]);
        float s = 0.f;
        for (int i = 0; i < CC; ++i) s += expf(logits[i] - m);
        out[g * CC + t] = logits[t] - m - logf(s);
    }
}

// ---------------- launch ----------------

extern "C" void kernel_launch(void* const* d_in, const int* in_sizes, int n_in,
                              void* d_out, int out_size, void* d_ws, size_t ws_size,
                              hipStream_t stream) {
    const float* x      = (const float*)d_in[0];
    const int*   ei     = (const int*)d_in[1];   // [2,E]: row0=src, row1=dst
    const int*   batch  = (const int*)d_in[2];
    const float* w_init = (const float*)d_in[3];
    const float* b_init = (const float*)d_in[4];
    const float* w_conv = (const float*)d_in[5];  // [2,128,128]
    const float* b_conv = (const float*)d_in[6];  // [2,128]
    const float* w_h1   = (const float*)d_in[7];
    const float* b_h1   = (const float*)d_in[8];
    const float* w_h2   = (const float*)d_in[9];
    const float* b_h2   = (const float*)d_in[10];
    float* out = (float*)d_out;
    (void)n_in; (void)in_sizes; (void)out_size; (void)ws_size;

    char* ws = (char*)d_ws;
    size_t off = 0;
    auto alloc = [&](size_t bytes) -> void* {
        void* p = ws + off;
        off += (bytes + 255) & ~(size_t)255;
        return p;
    };
    unsigned short* hAbf         = (unsigned short*)alloc((size_t)NN * HD * 2);  // bf16 node state
    unsigned*       g8           = (unsigned*)alloc((size_t)NN * 32 * 4);        // fp8 messages 12.8MB
    unsigned short* Wt           = (unsigned short*)alloc(3 * 16384 * 2);
    float*          dinv         = (float*)alloc((size_t)NN * 4);
    int*            row_start    = (int*)alloc((size_t)(NN + 1) * 4);
    int*            col          = (int*)alloc((size_t)EE * 4);
    unsigned*       ebuf         = (unsigned*)alloc((size_t)NBK * MAXB * 4);     // fixed regions 9.6MB
    unsigned*       cursor       = (unsigned*)alloc(256 * 4);
    float*          pooled       = (float*)alloc((size_t)GG * HD * 4);
    float*          cntg         = (float*)alloc((size_t)GG * 4);

    const int* srcp = ei;
    const int* dstp = ei + EE;

    k_prep_w<<<193, 256, 0, stream>>>(w_init, w_conv, w_conv + HD * HD, Wt,
                                      cursor, pooled, cntg);

    int nchunks = (EE + CH - 1) / CH;  // 196
    k_bscatter<<<nchunks, 512, 0, stream>>>(srcp, dstp, cursor, ebuf);
    k_bucket_csr<<<NBK, 1024, 0, stream>>>(ebuf, cursor, row_start, dinv, col);

    int gemm_grid = (NN + 127) / 128;  // 782
    int agg_grid = NN / 8;             // 12500 (exact)

    // layer 1 (f32 input)
    k_gemm_mfma<true><<<gemm_grid, 256, 0, stream>>>(x, Wt, dinv, g8);
    k_aggregate<<<agg_grid, 256, 0, stream>>>(g8, row_start, col, dinv, b_init, (uint2*)hAbf);
    // layer 2
    k_gemm_mfma<false><<<gemm_grid, 256, 0, stream>>>(hAbf, Wt + 16384, dinv, g8);
    k_aggregate<<<agg_grid, 256, 0, stream>>>(g8, row_start, col, dinv, b_conv, (uint2*)hAbf);
    // layer 3
    k_gemm_mfma<false><<<gemm_grid, 256, 0, stream>>>(hAbf, Wt + 2 * 16384, dinv, g8);
    k_aggregate<<<agg_grid, 256, 0, stream>>>(g8, row_start, col, dinv, b_conv + HD, (uint2*)hAbf);

    k_pool_partial<<<(NN + 127) / 128, 256, 0, stream>>>(hAbf, batch, pooled, cntg);
    k_head<<<GG, 128, 0, stream>>>(pooled, cntg, w_h1, b_h1, w_h2, b_h2, out);
}